// Round 10
// baseline (89.975 us; speedup 1.0000x reference)
//
#include <hip/hip_runtime.h>
#include <hip/hip_bf16.h>
#include <stdint.h>

#define Bn 2
#define Np 50000
#define Cc 81
#define CM1 80
#define KSEL 2048
#define NDET 100
#define NBUCK 2048
#define BUCK_BASE 0x3D000000u
#define BUCK_SHIFT 15
#define SELCAP 4096
#define IMG_W 1333.0f
#define IMG_H 800.0f
#define SCORE_TH 0.05f
#define MIN_SZ 0.01f
#define NMS_TH 0.5f
#define LBLOFF 1401.0f
#define BBOX_CLIP_F 4.135166556742356f
#define CHUNK 16
#define QCAP 320       // >= 16 proposals * 19 max emits (sum(softmax)=1)
#define BLKX 782       // ceil(Np / (4*CHUNK))
#define WPI  (BLKX*4)  // wave segments per image
#define RS_WPB 4       // runsort waves per block

typedef unsigned long long u64;
typedef unsigned int u32;

__device__ __forceinline__ u64 shfl64(u64 v, int src) {
  int lo = __shfl((int)(u32)v, src, 64);
  int hi = __shfl((int)(u32)(v >> 32), src, 64);
  return ((u64)(u32)hi << 32) | (u32)lo;
}

// Torchvision BoxCoder.decode + clip, non-contracted fp32 to match reference.
__device__ __forceinline__ void decode_box(int row, int c,
    const float* __restrict__ reg, const float* __restrict__ props,
    float& x1, float& y1, float& x2, float& y2) {
  const float4 pr = *reinterpret_cast<const float4*>(props + (size_t)row * 4);
  float w = __fsub_rn(pr.z, pr.x), h = __fsub_rn(pr.w, pr.y);
  float cx = __fadd_rn(pr.x, 0.5f * w), cy = __fadd_rn(pr.y, 0.5f * h);
  const float4 rel = *reinterpret_cast<const float4*>(reg + ((size_t)row * Cc + c) * 4);
  float dx = __fdiv_rn(rel.x, 10.f), dy = __fdiv_rn(rel.y, 10.f);
  float dw = fminf(__fdiv_rn(rel.z, 5.f), BBOX_CLIP_F);
  float dh = fminf(__fdiv_rn(rel.w, 5.f), BBOX_CLIP_F);
  float pcx = __fadd_rn(__fmul_rn(dx, w), cx);
  float pcy = __fadd_rn(__fmul_rn(dy, h), cy);
  float pw = __fmul_rn(expf(dw), w);
  float ph = __fmul_rn(expf(dh), h);
  x1 = fminf(fmaxf(__fsub_rn(pcx, 0.5f * pw), 0.f), IMG_W);
  y1 = fminf(fmaxf(__fsub_rn(pcy, 0.5f * ph), 0.f), IMG_H);
  x2 = fminf(fmaxf(__fadd_rn(pcx, 0.5f * pw), 0.f), IMG_W);
  y2 = fminf(fmaxf(__fadd_rn(pcy, 0.5f * ph), 0.f), IMG_H);
}

// Decode a key and write clipped box/score/label to the SoA at position pos.
__device__ __forceinline__ void decode_key_to_sel(u64 key, int b,
    const float* __restrict__ reg, const float* __restrict__ props,
    float* __restrict__ S, u32 pos) {
  const u32 sb = (u32)(key >> 32);
  const u32 idx = ~(u32)key;
  const int n_ = (int)(idx / CM1);
  const int c = (int)(idx % CM1) + 1;
  float x1, y1, x2, y2;
  decode_box(b * Np + n_, c, reg, props, x1, y1, x2, y2);
  S[0 * SELCAP + pos] = x1; S[1 * SELCAP + pos] = y1;
  S[2 * SELCAP + pos] = x2; S[3 * SELCAP + pos] = y2;
  S[4 * SELCAP + pos] = __uint_as_float(sb);
  S[5 * SELCAP + pos] = (float)c;
}

// Quad-split softmax over one wave's 16-proposal LDS slab. Reduce orders
// bit-identical to rounds 3..9 (all matched the reference exactly).
#define SOFTMAX_PROLOG(S)                                            \
  const int p = lane >> 2, qd = lane & 3;                            \
  const int base = p * Cc + qd * 21;                                 \
  const int cnt_k = (qd == 3) ? 18 : 21;                             \
  float ev[21];                                                      \
  _Pragma("unroll")                                                  \
  for (int k = 0; k < 21; ++k)                                       \
    ev[k] = (k < cnt_k) ? (S)[base + k] : -3.4e38f;                  \
  float m = ev[0];                                                   \
  _Pragma("unroll")                                                  \
  for (int k = 1; k < 21; ++k) m = fmaxf(m, ev[k]);                  \
  m = fmaxf(m, __shfl_xor(m, 1, 64));                                \
  m = fmaxf(m, __shfl_xor(m, 2, 64));                                \
  float s = 0.f;                                                     \
  _Pragma("unroll")                                                  \
  for (int k = 0; k < 21; ++k) {                                     \
    ev[k] = (k < cnt_k) ? expf(ev[k] - m) : 0.f;                     \
    s += ev[k];                                                      \
  }                                                                  \
  s += __shfl_xor(s, 1, 64);                                         \
  s += __shfl_xor(s, 2, 64);                                         \
  const float thr = SCORE_TH * s;

// Stage 16 proposals x 81 logits (324 float4, coalesced) into the wave slab.
#define STAGE_LOGITS(S, src)                                         \
  _Pragma("unroll")                                                  \
  for (int i = 0; i < 6; ++i) {                                      \
    const int f4 = i * 64 + lane;                                    \
    if (f4 < (CHUNK * Cc) / 4) {                                     \
      const float4 v = *reinterpret_cast<const float4*>((src) + (size_t)f4 * 4); \
      *reinterpret_cast<float4*>(&(S)[f4 * 4]) = v;                  \
    }                                                                \
  }

// Pass A (pure stream): softmax -> emit (score>0.05) keys straight to the
// PRIVATE per-wave global segment (ballot-compacted, no atomics) + LDS
// histogram -> fire-and-forget global hist flush. No decode here.
__global__ __launch_bounds__(256, 4) void passA_kernel(
    const float* __restrict__ logits, u64* __restrict__ wseg,
    u32* __restrict__ wcnt, u32* __restrict__ ghist)
{
  __shared__ __align__(16) float stg[4][CHUNK * Cc];   // 20736 B
  __shared__ u32 hist[NBUCK];                          // 8192 B
  const int b = blockIdx.y;
  const int tid = threadIdx.x;
  const int wave = tid >> 6, lane = tid & 63;
  for (int i = tid; i < NBUCK; i += 256) hist[i] = 0;
  __syncthreads();

  const int wslot = (blockIdx.x << 2) + wave;
  const int n0 = wslot * CHUNK;
  u64* seg = wseg + (size_t)(b * WPI + wslot) * QCAP;
  u32 wout = 0;
  if (n0 < Np) {
    float* S = stg[wave];
    STAGE_LOGITS(S, logits + ((size_t)b * Np + n0) * Cc)
    SOFTMAX_PROLOG(S)
    const int n_ = n0 + p;
    #pragma unroll
    for (int k = 0; k < 21; ++k) {
      const int c = qd * 21 + k;
      bool emit = false;
      u64 key = 0; u32 bk = 0;
      if (c > 0 && ev[k] > thr) {
        const u32 sb = __float_as_uint(__fdiv_rn(ev[k], s));
        const u32 idx = (u32)(n_ * CM1 + (c - 1));
        key = ((u64)sb << 32) | (u32)(~idx);
        bk = (sb - BUCK_BASE) >> BUCK_SHIFT;
        if (bk > (u32)(NBUCK - 1)) bk = NBUCK - 1;
        emit = true;
      }
      const u64 bal = __ballot(emit);
      if (emit) {
        seg[wout + (u32)__popcll(bal & ((1ull << lane) - 1ull))] = key;
        atomicAdd(&hist[bk], 1u);
      }
      wout += (u32)__popcll(bal);
    }
  }
  if (lane == 0) wcnt[b * WPI + wslot] = wout;   // 0 for inactive tail waves
  __syncthreads();
  for (int i = tid; i < NBUCK; i += 256) {
    const u32 v = hist[i];
    if (v) atomicAdd(&ghist[b * NBUCK + i], v);   // no return use: fire-and-forget
  }
}

// Per image: T = largest bucket with inclusive suffix >= KSEL (0 if total
// < KSEL); exclusive suffix offsets; total selected (clamped to SELCAP).
__global__ void thresh_kernel(const u32* __restrict__ ghist, u32* __restrict__ gT,
                              u32* __restrict__ gTot, u32* __restrict__ boffs) {
  const int b = blockIdx.x;
  const int lane = threadIdx.x;  // 64 threads
  const u32* h = ghist + b * NBUCK;
  u32* bo = boffs + b * NBUCK;
  const int SEG = NBUCK / 64;
  u32 segsum = 0;
  for (int t = 0; t < SEG; ++t) segsum += h[lane * SEG + t];
  u32 suf = segsum;
  #pragma unroll
  for (int o = 1; o < 64; o <<= 1) {
    const u32 v = (u32)__shfl_down((int)suf, o, 64);
    if (lane + o < 64) suf += v;
  }
  u32 acc = suf - segsum;   // count in buckets strictly above this segment
  int myT = -1; u32 totv = 0;
  for (int t = SEG - 1; t >= 0; --t) {
    const int bk = lane * SEG + t;
    bo[bk] = acc;
    acc += h[bk];
    if (myT < 0 && acc >= (u32)KSEL) { myT = bk; totv = acc; }
  }
  int Tg = myT;
  #pragma unroll
  for (int o = 32; o; o >>= 1) Tg = max(Tg, __shfl_xor(Tg, o, 64));
  if (Tg < 0) {
    if (lane == 0) { gT[b] = 0u; gTot[b] = (acc < (u32)SELCAP) ? acc : (u32)SELCAP; }
  } else if (myT == Tg) {
    gT[b] = (u32)Tg;
    gTot[b] = (totv < (u32)SELCAP) ? totv : (u32)SELCAP;
  }
}

// Scatter: wave-per-segment. Keys with bucket >= T (~2100/image) are
// decoded + minsize-filtered HERE (deferred from passA; drops are
// expected-zero on this distribution), then placed via per-bucket fill
// atomics.
__global__ __launch_bounds__(256) void scatter_kernel(
    const u64* __restrict__ wseg, const u32* __restrict__ wcnt,
    const u32* __restrict__ gT, const u32* __restrict__ boffs,
    u32* __restrict__ bfill, u64* __restrict__ skeys,
    const float* __restrict__ reg, const float* __restrict__ props)
{
  const int b = blockIdx.y;
  const u32 T = gT[b];
  const int wave = threadIdx.x >> 6, lane = threadIdx.x & 63;
  const u32 sgi = blockIdx.x * 4 + wave;
  if (sgi >= (u32)WPI) return;
  const u32 cnt = wcnt[b * WPI + sgi];
  const u64* seg = wseg + (size_t)(b * WPI + sgi) * QCAP;
  for (u32 i = lane; i < cnt; i += 64) {
    const u64 key = seg[i];
    const u32 sb = (u32)(key >> 32);
    u32 bk = (sb - BUCK_BASE) >> BUCK_SHIFT;
    if (bk > (u32)(NBUCK - 1)) bk = NBUCK - 1;
    if (bk >= T) {
      const u32 idx = ~(u32)key;
      const int pn = (int)(idx / CM1);
      const int c = (int)(idx % CM1) + 1;
      float x1, y1, x2, y2;
      decode_box(b * Np + pn, c, reg, props, x1, y1, x2, y2);
      if (__fsub_rn(x2, x1) >= MIN_SZ && __fsub_rn(y2, y1) >= MIN_SZ) {
        const u32 pos = boffs[b * NBUCK + bk] + atomicAdd(&bfill[b * NBUCK + bk], 1u);
        if (pos < (u32)SELCAP) skeys[(size_t)b * SELCAP + pos] = key;
      }
    }
  }
}

// Runsort + decode: wave-per-bucket register rank sort (runs avg ~10),
// then each lane decodes its own key and writes the SoA at its sorted
// position. Zero-fills score for any hist-vs-fill hole (minsize drops).
__global__ __launch_bounds__(256) void runsort_kernel(
    const u64* __restrict__ skeys, const u32* __restrict__ gT,
    const u32* __restrict__ boffs, const u32* __restrict__ bfill,
    const u32* __restrict__ ghist,
    const float* __restrict__ reg, const float* __restrict__ props,
    float* __restrict__ sel)
{
  const int b = blockIdx.y;
  const int wave = threadIdx.x >> 6, lane = threadIdx.x & 63;
  const u32 bk = blockIdx.x * RS_WPB + wave;
  if (bk >= (u32)NBUCK || bk < gT[b]) return;
  const u32 start = boffs[b * NBUCK + bk];
  if (start >= (u32)SELCAP) return;
  u32 Lp = bfill[b * NBUCK + bk];
  u32 Lh = ghist[b * NBUCK + bk];
  if (start + Lp > (u32)SELCAP) Lp = SELCAP - start;
  if (start + Lh > (u32)SELCAP) Lh = SELCAP - start;
  float* S = sel + (size_t)b * 6 * SELCAP;
  for (u32 j = Lp + lane; j < Lh; j += 64) S[4 * SELCAP + start + j] = 0.f;
  if (Lp == 0) return;
  const u64* run = skeys + (size_t)b * SELCAP + start;
  if (Lp <= 128u) {
    const u64 k0 = (lane < (int)Lp) ? run[lane] : 0ull;
    const u64 k1 = (64 + lane < (int)Lp) ? run[64 + lane] : 0ull;
    u32 r0 = 0, r1 = 0;
    #pragma unroll
    for (int l = 0; l < 64; ++l) {
      const u64 o0 = shfl64(k0, l);
      const u64 o1 = shfl64(k1, l);
      r0 += (o0 > k0) + (o1 > k0);
      r1 += (o0 > k1) + (o1 > k1);
    }
    if (lane < (int)Lp) decode_key_to_sel(k0, b, reg, props, S, start + r0);
    if (64 + lane < (int)Lp) decode_key_to_sel(k1, b, reg, props, S, start + r1);
  } else {
    // Slow path (never expected): L2-hot global rank loop.
    for (u32 i = lane; i < Lp; i += 64) {
      const u64 k = run[i];
      u32 r = 0;
      for (u32 q = 0; q < Lp; ++q) r += (run[q] > k);
      decode_key_to_sel(k, b, reg, props, S, start + r);
    }
  }
}

// Tail: SINGLE WAVE per image, NMS only (zero barriers). Coalesced SoA
// chunk loads, shfl-broadcast per-keep suppression, early-exit at 100.
__global__ __launch_bounds__(64) void tail_kernel(
    const float* __restrict__ sel, const u32* __restrict__ gTot,
    float* __restrict__ out)
{
  __shared__ float kox1[NDET], koy1[NDET], kox2[NDET], koy2[NDET], kar[NDET];
  __shared__ float kx1[NDET], ky1[NDET], kx2[NDET], ky2[NDET], ksc[NDET], klb[NDET];
  const int b = blockIdx.x;
  const int lane = threadIdx.x;
  const u32 total = gTot[b];
  const float* S = sel + (size_t)b * 6 * SELCAP;
  int kc = 0;
  for (u32 bbase = 0; bbase < total && kc < NDET; bbase += 64) {
    const u32 pos = bbase + lane;
    const bool inb = pos < total;
    float x1 = 0, y1 = 0, x2 = 0, y2 = 0, sc = 0, lb = 0;
    if (inb) {
      x1 = S[0 * SELCAP + pos]; y1 = S[1 * SELCAP + pos];
      x2 = S[2 * SELCAP + pos]; y2 = S[3 * SELCAP + pos];
      sc = S[4 * SELCAP + pos]; lb = S[5 * SELCAP + pos];
    }
    const float offv = __fmul_rn(lb, LBLOFF);
    const float ox1 = __fadd_rn(x1, offv), oy1 = __fadd_rn(y1, offv);
    const float ox2 = __fadd_rn(x2, offv), oy2 = __fadd_rn(y2, offv);
    const float ar = __fmul_rn(__fsub_rn(ox2, ox1), __fsub_rn(oy2, oy1));
    const bool valid = inb && (sc > 0.f);
    bool sup = false;
    for (int k = 0; k < kc; ++k) {
      const float ltx = fmaxf(ox1, kox1[k]), lty = fmaxf(oy1, koy1[k]);
      const float rbx = fminf(ox2, kox2[k]), rby = fminf(oy2, koy2[k]);
      const float wx = fmaxf(__fsub_rn(rbx, ltx), 0.f);
      const float wy = fmaxf(__fsub_rn(rby, lty), 0.f);
      const float inter = __fmul_rn(wx, wy);
      const float denom = __fadd_rn(__fsub_rn(__fadd_rn(ar, kar[k]), inter), 1e-9f);
      if (__fdiv_rn(inter, denom) > NMS_TH) sup = true;
    }
    u64 rem = __ballot(sup) | ~__ballot(valid);
    u64 todo = ~rem;
    while (todo && kc < NDET) {
      const int jb = (int)__builtin_ctzll(todo);
      const float bx1 = __shfl(ox1, jb, 64), by1 = __shfl(oy1, jb, 64);
      const float bx2 = __shfl(ox2, jb, 64), by2 = __shfl(oy2, jb, 64);
      const float ba  = __shfl(ar, jb, 64);
      if (lane == jb) {
        kox1[kc] = ox1; koy1[kc] = oy1; kox2[kc] = ox2; koy2[kc] = oy2; kar[kc] = ar;
        kx1[kc] = x1; ky1[kc] = y1; kx2[kc] = x2; ky2[kc] = y2; ksc[kc] = sc; klb[kc] = lb;
      }
      const float ltx = fmaxf(ox1, bx1), lty = fmaxf(oy1, by1);
      const float rbx = fminf(ox2, bx2), rby = fminf(oy2, by2);
      const float wx = fmaxf(__fsub_rn(rbx, ltx), 0.f);
      const float wy = fmaxf(__fsub_rn(rby, lty), 0.f);
      const float inter = __fmul_rn(wx, wy);
      const float denom = __fadd_rn(__fsub_rn(__fadd_rn(ar, ba), inter), 1e-9f);
      const u64 w = __ballot(__fdiv_rn(inter, denom) > NMS_TH);
      rem |= w;
      todo &= ~rem;
      todo &= ~(1ull << jb);
      ++kc;
    }
  }
  // Output: first min(kc,100) kept, padded with zeros / label -1.
  const int kcl = (kc < NDET) ? kc : NDET;
  for (int k = lane; k < NDET; k += 64) {
    float bx1 = 0, by1 = 0, bx2 = 0, by2 = 0, sc = 0, lb = -1.f;
    if (k < kcl) {
      bx1 = kx1[k]; by1 = ky1[k]; bx2 = kx2[k]; by2 = ky2[k];
      sc = ksc[k]; lb = klb[k];
    }
    float* ob = out + (size_t)b * NDET * 4;
    ob[k * 4 + 0] = bx1; ob[k * 4 + 1] = by1;
    ob[k * 4 + 2] = bx2; ob[k * 4 + 3] = by2;
    out[Bn * NDET * 4 + b * NDET + k] = sc;
    out[Bn * NDET * 4 + Bn * NDET + b * NDET + k] = lb;
  }
}

extern "C" void kernel_launch(void* const* d_in, const int* in_sizes, int n_in,
                              void* d_out, int out_size, void* d_ws, size_t ws_size,
                              hipStream_t stream) {
  const float* logits = (const float*)d_in[0];
  const float* reg    = (const float*)d_in[1];
  const float* props  = (const float*)d_in[2];
  float* out = (float*)d_out;
  char* ws = (char*)d_ws;

  // Layout: [header | ghist | bfill]  <- memset 0 each call (32 KB)
  //         [boffs | skeys | sel | wcnt | wseg] <- count/overwrite-guarded
  u32* gT   = (u32*)ws;                        // 2 u32
  u32* gTot = (u32*)(ws + 16);                 // 2 u32
  size_t off = 64;
  u32* ghist = (u32*)(ws + off); off += (size_t)Bn * NBUCK * 4;    // 16 KB
  u32* bfill = (u32*)(ws + off); off += (size_t)Bn * NBUCK * 4;    // 16 KB
  const size_t memset_bytes = off;
  u32* boffs = (u32*)(ws + off); off += (size_t)Bn * NBUCK * 4;    // 16 KB
  u64* skeys = (u64*)(ws + off); off += (size_t)Bn * SELCAP * 8;   // 64 KB
  float* sel = (float*)(ws + off); off += (size_t)Bn * 6 * SELCAP * 4;  // 192 KB
  u32* wcnt  = (u32*)(ws + off); off += (size_t)Bn * WPI * 4;      // 25 KB
  off = (off + 255) & ~(size_t)255;
  u64* wseg  = (u64*)(ws + off); off += (size_t)Bn * WPI * QCAP * 8;   // 16 MB
  (void)ws_size;

  hipMemsetAsync(d_ws, 0, memset_bytes, stream);
  passA_kernel<<<dim3(BLKX, Bn), 256, 0, stream>>>(logits, wseg, wcnt, ghist);
  thresh_kernel<<<dim3(Bn), 64, 0, stream>>>(ghist, gT, gTot, boffs);
  scatter_kernel<<<dim3((WPI + 3) / 4, Bn), 256, 0, stream>>>(wseg, wcnt, gT, boffs, bfill, skeys, reg, props);
  runsort_kernel<<<dim3(NBUCK / RS_WPB, Bn), 256, 0, stream>>>(skeys, gT, boffs, bfill, ghist, reg, props, sel);
  tail_kernel<<<dim3(Bn), 64, 0, stream>>>(sel, gTot, out);
}